// Round 8
// baseline (862.415 us; speedup 1.0000x reference)
//
#include <hip/hip_runtime.h>

#define B_SZ 256
#define F_SZ 4
#define M_SZ 256
#define D_SZ 8192
#define NITER 10

typedef signed char i8;
typedef unsigned long long u64;
typedef signed char c16 __attribute__((ext_vector_type(16)));
typedef int v4i __attribute__((ext_vector_type(4)));

#define NBFM (B_SZ * F_SZ * M_SZ)   // 262144

// ---- workspace layout (bytes) ----
#define OFF_CB    ((size_t)0)          // i8  [F][M][D]      8 MB
#define OFF_CBFB  ((size_t)8  << 20)   // u8  PACKED frag-linear B 1 MB
#define OFF_IN8   ((size_t)16 << 20)   // i8  [B][D]         2 MB
#define OFF_CBBT  ((size_t)18 << 20)   // u64 [F][128][M]    1 MB
#define OFF_INB   ((size_t)19 << 20)   // u64 [B][128]       256 KB
#define OFF_ESB   ((size_t)20 << 20)   // u64 [B][F][128]    1 MB  (est signs, buffer 0)
#define OFF_EZB   ((size_t)21 << 20)   // u64 [B][F][128]    1 MB  (est zeros, buffer 0)
#define OFF_AF01  ((size_t)22 << 20)   // i8  frag-linear A planes 0,1  512 KB (iter1 only)
#define OFF_AF2   (OFF_AF01 + ((size_t)512 << 10))   // i8 plane 2, 256 KB (iter1 only)
#define OFF_P1    ((size_t)23 << 20)   // i32 [24][B*F*M]    24 MB  (iter1 partials; dead after k_digits1)
#define OFF_ESB1  ((size_t)40 << 20)   // u64 est signs buffer 1 (inside dead P1 region)
#define OFF_EZB1  ((size_t)41 << 20)   // u64 est zeros buffer 1
#define OFF_S32   ((size_t)48 << 20)   // i32 [F][D]         128 KB
#define OFF_PDIG  (OFF_S32 + (size_t)F_SZ * D_SZ * 4)   // i8 [3][F][D] 96 KB
#define OFF_CHG   (OFF_PDIG + (size_t)3 * F_SZ * D_SZ)  // int[16]

// frag-linear A slot index for (f, b, m)
__device__ __forceinline__ size_t afslot(int f, int b, int m) {
  return (size_t)(((f * 4 + (b >> 6)) * 8 + (m >> 5)) * 4 + ((b >> 4) & 3)) * 64
         + ((m >> 3) & 3) * 16 + (b & 15);
}

// expand 8 packed sign bits (bit=1 => -1) to 8 i8 bytes {+1,-1}
__device__ __forceinline__ long expand_pm1(unsigned b) {
  u64 x = (u64)b * 0x0101010101010101ULL;
  x &= 0x8040201008040201ULL;
  x += 0x00406070787C7E7FULL;
  x &= 0x8080808080808080ULL;
  u64 s = x >> 7;
  return (long)(0x0101010101010101ULL ^ (s * 0xFEULL));
}

// ---------------- converts / init ----------------

__global__ __launch_bounds__(256) void k_cvt_cb(const float* __restrict__ src,
                                                i8* __restrict__ cb, unsigned char* __restrict__ cbFb) {
  __shared__ i8 tile[32][33];   // [m][d]
  const int bid = blockIdx.x;           // 8192 = 4f * 8mt * 256dt
  const int f = bid >> 11;
  const int rem = bid & 2047;
  const int m0 = (rem >> 8) << 5;
  const int d0 = (rem & 255) << 5;
  const int t = threadIdx.x;
  const int i = t >> 3, j = (t & 7) << 2;
  const float4 v = *(const float4*)(src + ((size_t)(f * M_SZ + m0 + i)) * D_SZ + d0 + j);
  char4 c;
  c.x = v.x > 0.f ? 1 : -1;
  c.y = v.y > 0.f ? 1 : -1;
  c.z = v.z > 0.f ? 1 : -1;
  c.w = v.w > 0.f ? 1 : -1;
  *(char4*)(cb + ((size_t)(f * M_SZ + m0 + i)) * D_SZ + d0 + j) = c;
  tile[i][j + 0] = c.x; tile[i][j + 1] = c.y; tile[i][j + 2] = c.z; tile[i][j + 3] = c.w;
  __syncthreads();
  if (t < 128) {
    const int mg = t >> 5;       // m-octet within the 32-m (ks) group
    const int dd = t & 31;
    const int d = d0 + dd;
    const int dt = d >> 7, dsub = (d >> 4) & 7, dlo = d & 15;
    const int ks = m0 >> 5;
    unsigned pk = 0;
    #pragma unroll
    for (int jj = 0; jj < 8; ++jj)
      pk |= ((((unsigned char)tile[mg * 8 + jj][dd]) >> 7) & 1u) << jj;
    cbFb[(size_t)(f * 64 + dt) * 4096 + (ks * 8 + dsub) * 64 + mg * 16 + dlo] = (unsigned char)pk;
  }
}

__global__ __launch_bounds__(256) void k_cvt_in(const float* __restrict__ src, i8* __restrict__ dst) {
  const int idx = blockIdx.x * 256 + threadIdx.x;   // 524288 float4s
  const float4 v = ((const float4*)src)[idx];
  char4 c;
  c.x = v.x > 0.f ? 1 : -1;
  c.y = v.y > 0.f ? 1 : -1;
  c.z = v.z > 0.f ? 1 : -1;
  c.w = v.w > 0.f ? 1 : -1;
  ((char4*)dst)[idx] = c;
}

__global__ __launch_bounds__(256) void k_pack_cb(const i8* __restrict__ cb, u64* __restrict__ cbbT) {
  const int id = blockIdx.x * 256 + threadIdx.x;   // 131072 = f*32768 + w*256 + m
  const int f = id >> 15;
  const int rem = id & 32767;
  const int w = rem >> 8;
  const int m = rem & 255;
  const i8* src = cb + ((size_t)(f * M_SZ + m)) * D_SZ + w * 64;
  u64 r = 0;
  #pragma unroll
  for (int k = 0; k < 4; ++k) {
    c16 v = *(const c16*)(src + k * 16);
    u64 part = 0;
    #pragma unroll
    for (int j = 0; j < 16; ++j) part |= ((u64)(((unsigned char)v[j]) >> 7)) << j;
    r |= part << (k * 16);
  }
  cbbT[((size_t)(f * 128 + w)) * 256 + m] = r;
}

__global__ __launch_bounds__(256) void k_pack_in(const i8* __restrict__ in8, u64* __restrict__ inb) {
  const int id = blockIdx.x * 256 + threadIdx.x;   // 32768 = b*128 + w
  const int b = id >> 7;
  const int w = id & 127;
  const i8* src = in8 + (size_t)b * D_SZ + w * 64;
  u64 r = 0;
  #pragma unroll
  for (int k = 0; k < 4; ++k) {
    c16 v = *(const c16*)(src + k * 16);
    u64 part = 0;
    #pragma unroll
    for (int j = 0; j < 16; ++j) part |= ((u64)(((unsigned char)v[j]) >> 7)) << j;
    r |= part << (k * 16);
  }
  inb[(size_t)b * 128 + w] = r;
}

__global__ __launch_bounds__(256) void k_S(const i8* __restrict__ cb, int* __restrict__ S) {
  const int id = blockIdx.x * 256 + threadIdx.x;    // 32768 = [f][d]
  const int f = id >> 13, d = id & 8191;
  const i8* p = cb + (size_t)f * M_SZ * D_SZ + d;
  int s = 0;
  for (int m = 0; m < M_SZ; ++m) s += p[(size_t)m * D_SZ];
  S[id] = s;
}

// P' = P/8 (exact), 3 radix-255 signed digits in [-127,127]
__global__ __launch_bounds__(256) void k_P(const int* __restrict__ S, i8* __restrict__ pdig) {
  const int d = blockIdx.x * 256 + threadIdx.x;     // 8192
  const int s0 = S[d], s1 = S[D_SZ + d], s2 = S[2 * D_SZ + d], s3 = S[3 * D_SZ + d];
  int P[4];
  P[0] = s1 * s2 * s3;
  P[1] = s0 * s2 * s3;
  P[2] = s0 * s1 * s3;
  P[3] = s0 * s1 * s2;
  for (int f = 0; f < 4; ++f) {
    int x = P[f] >> 3;
    #pragma unroll
    for (int p = 0; p < 2; ++p) {
      const int y = x + 127;
      const int q = (y >= 0) ? (y / 255) : -((-y + 254) / 255);
      const int dg = x - q * 255;
      pdig[((size_t)(p * F_SZ + f)) * D_SZ + d] = (i8)dg;
      x = q;
    }
    pdig[((size_t)(2 * F_SZ + f)) * D_SZ + d] = (i8)x;
  }
}

// ---------------- iteration-1 stage A (MFMA, 3 digit planes of P/8) ----------------

__global__ __launch_bounds__(256) void ga2_kernel(
    const i8* __restrict__ in8, const i8* __restrict__ cb,
    const i8* __restrict__ pdig, int* __restrict__ p1)
{
  __shared__ __align__(16) i8 lA[64 * 48];
  __shared__ __align__(16) i8 lB[128 * 48];

  const int bid = blockIdx.x;
  const int s = bid & 7;
  const int r = bid >> 3;
  const int p = r % 3;
  const int q = r / 3;
  const int f = q & 3;
  const int ct = q >> 2;
  const int b0 = (ct >> 1) * 64;
  const int m0 = (ct & 1) * 128;
  const int ksteps = 32;
  const int kbase = s << 10;

  const int t = threadIdx.x;
  const int lane = t & 63;
  const int wv = t >> 6;
  const int wrow = (wv >> 1) * 32;
  const int wcol = (wv & 1) * 64;

  const int arow = t >> 1;
  const int aoff = (t & 1) * 16;
  const i8* pB  = cb   + ((size_t)(f * M_SZ + m0 + arow)) * D_SZ + aoff;
  const i8* pDg = pdig + ((size_t)(p * F_SZ + f)) * D_SZ + aoff;
  const i8* pIn = in8  + (size_t)(b0 + arow) * D_SZ + aoff;

  v4i acc[2][4];
  #pragma unroll
  for (int tr = 0; tr < 2; ++tr)
    #pragma unroll
    for (int tc = 0; tc < 4; ++tc) acc[tr][tc] = 0;

  c16 va = 0, vb = 0;
  {
    const int kk = kbase;
    vb = (*(const c16*)(pB + kk)) * (*(const c16*)(pDg + kk));
    if (t < 128) va = *(const c16*)(pIn + kk);
  }

  for (int j = 0; j < ksteps; ++j) {
    c16 sa = va, sb = vb;
    if (j + 1 < ksteps) {
      const int kk = kbase + (j + 1) * 32;
      vb = (*(const c16*)(pB + kk)) * (*(const c16*)(pDg + kk));
      if (t < 128) va = *(const c16*)(pIn + kk);
    }
    __syncthreads();
    if (t < 128) *(c16*)&lA[arow * 48 + aoff] = sa;
    *(c16*)&lB[arow * 48 + aoff] = sb;
    __syncthreads();

    const int rsel = lane & 15;
    const int kq = (lane >> 4) * 8;
    long af[2], bf[4];
    #pragma unroll
    for (int tr = 0; tr < 2; ++tr) af[tr] = *(const long*)&lA[(wrow + tr * 16 + rsel) * 48 + kq];
    #pragma unroll
    for (int tc = 0; tc < 4; ++tc) bf[tc] = *(const long*)&lB[(wcol + tc * 16 + rsel) * 48 + kq];
    #pragma unroll
    for (int tr = 0; tr < 2; ++tr)
      #pragma unroll
      for (int tc = 0; tc < 4; ++tc)
        acc[tr][tc] = __builtin_amdgcn_mfma_i32_16x16x32_i8(af[tr], bf[tc], acc[tr][tc], 0, 0, 0);
  }

  const int colb = lane & 15;
  const int rowq = (lane >> 4) * 4;
  const size_t obase = (size_t)(p * 8 + s) * NBFM;
  #pragma unroll
  for (int tr = 0; tr < 2; ++tr)
    #pragma unroll
    for (int tc = 0; tc < 4; ++tc)
      #pragma unroll
      for (int rr = 0; rr < 4; ++rr) {
        const int b = b0 + wrow + tr * 16 + rowq + rr;
        const int m = m0 + wcol + tc * 16 + colb;
        p1[obase + (((size_t)(b * F_SZ + f)) << 8) + m] = acc[tr][tc][rr];
      }
}

// recombine 24 slices -> 3 radix-256 digits, frag-linear
__global__ __launch_bounds__(256) void k_digits1(const int* __restrict__ p1,
                                                 i8* __restrict__ aF01, i8* __restrict__ aF2) {
  const int idx = blockIdx.x * 256 + threadIdx.x;
  long long g[3];
  #pragma unroll
  for (int p = 0; p < 3; ++p) {
    long long gg = 0;
    #pragma unroll
    for (int s = 0; s < 8; ++s) gg += (long long)p1[(size_t)(p * 8 + s) * NBFM + idx];
    g[p] = gg;
  }
  const long long sim = g[0] + 255LL * g[1] + 65025LL * g[2];
  int x = (int)sim;
  const int r1 = (x + 128) >> 8;
  const int d0 = x - (r1 << 8);
  const int r2 = (r1 + 128) >> 8;
  const int d1 = r1 - (r2 << 8);
  const int bf = idx >> 8;        // b*4+f
  const int m = idx & 255;
  const int b = bf >> 2, f = bf & 3;
  const size_t sl = afslot(f, b, m);
  const int by = m & 7;
  aF01[sl * 16 + by] = (i8)d0;
  aF01[sl * 16 + 8 + by] = (i8)d1;
  aF2[sl * 8 + by] = (i8)r2;
}

// ---------------- iteration-1 stage B (NP=3, packed B expanded in regs; writes buffer 0) ----------------

__global__ __launch_bounds__(256, 3) void gb_first_k(
    const i8* __restrict__ aF01, const i8* __restrict__ aF2, const unsigned char* __restrict__ cbFb,
    u64* __restrict__ esb, u64* __restrict__ ezb,
    const int* __restrict__ S32, int* __restrict__ changed, int it)
{
  const int bid = blockIdx.x;
  const int xcd = bid & 7;
  const int f = xcd >> 1;
  const int r = bid >> 3;
  const int bt = r & 3;
  const int dt = (xcd & 1) * 32 + (r >> 2);
  const int d0 = dt * 128;

  const int t = threadIdx.x;
  const int lane = t & 63;
  const int wv = t >> 6;
  const int wrow = (wv >> 1) * 32;
  const int wcol = (wv & 1) * 64;
  const int tb = wcol >> 4;
  const int sub0 = wrow >> 4;
  const int b0 = bt * 64;

  v4i acc[3][2][4];
  #pragma unroll
  for (int pp = 0; pp < 3; ++pp)
    #pragma unroll
    for (int tr = 0; tr < 2; ++tr)
      #pragma unroll
      for (int tc = 0; tc < 4; ++tc) acc[pp][tr][tc] = 0;

  const i8* pA = aF01 + ((size_t)(f * 4 + bt)) * 32768;
  const i8* pA2 = aF2 + ((size_t)(f * 4 + bt)) * 16384;
  const unsigned char* pb = cbFb + (size_t)(f * 64 + dt) * 4096 + tb * 64 + lane;

  #pragma unroll
  for (int ks = 0; ks < 8; ++ks) {
    long bf[4];
    #pragma unroll
    for (int tc = 0; tc < 4; ++tc)
      bf[tc] = expand_pm1(pb[ks * 512 + tc * 64]);
    long af[3][2];
    #pragma unroll
    for (int tr = 0; tr < 2; ++tr) {
      union { c16 v; long l[2]; } x;
      x.v = *(const c16*)(pA + ((size_t)((ks * 4 + sub0 + tr) * 64 + lane)) * 16);
      af[0][tr] = x.l[0];
      af[1][tr] = x.l[1];
      af[2][tr] = *(const long*)(pA2 + ((size_t)((ks * 4 + sub0 + tr) * 64 + lane)) * 8);
    }
    #pragma unroll
    for (int pp = 0; pp < 3; ++pp)
      #pragma unroll
      for (int tr = 0; tr < 2; ++tr)
        #pragma unroll
        for (int tc = 0; tc < 4; ++tc)
          acc[pp][tr][tc] = __builtin_amdgcn_mfma_i32_16x16x32_i8(af[pp][tr], bf[tc], acc[pp][tr][tc], 0, 0, 0);
  }

  bool chl = false;
  const int colb = lane & 15;

  #pragma unroll
  for (int tr = 0; tr < 2; ++tr) {
    unsigned long long bs[4][4], bz[4][4];
    #pragma unroll
    for (int rr = 0; rr < 4; ++rr)
      #pragma unroll
      for (int tc = 0; tc < 4; ++tc) {
        int o = acc[0][tr][tc][rr] + acc[1][tr][tc][rr] * 256 + acc[2][tr][tc][rr] * 65536;
        bs[rr][tc] = __ballot(o < 0);
        bz[rr][tc] = __ballot(o == 0);
        const int sg = (o > 0) - (o < 0);
        const int d = d0 + wcol + tc * 16 + colb;
        chl |= (sg != S32[f * D_SZ + d]);
      }
    u64 ws = 0, wz = 0;
    #pragma unroll
    for (int rl = 0; rl < 16; ++rl) {
      const int g = rl >> 2, rr = rl & 3;
      u64 vs = 0, vz = 0;
      #pragma unroll
      for (int tc = 0; tc < 4; ++tc) {
        vs |= ((bs[rr][tc] >> (g * 16)) & 0xFFFFull) << (tc * 16);
        vz |= ((bz[rr][tc] >> (g * 16)) & 0xFFFFull) << (tc * 16);
      }
      if (lane == rl) { ws = vs; wz = vz; }
    }
    if (lane < 16) {
      const int row = b0 + wrow + tr * 16 + lane;
      const size_t wi = ((size_t)(row * 4 + f)) * 128 + ((d0 + wcol) >> 6);
      esb[wi] = ws;
      ezb[wi] = wz;
    }
  }
  if (__any(chl)) { if (lane == 0) atomicOr(&changed[it], 1); }
}

// ---------------- merged per-iteration kernel: sim (bitwise) + GEMM + sign, double-buffered ----------------
// grid 256 = bg(16 b-rows)(16) x f(4) x dq(4 d-quarters); 512 threads (8 waves).
// Reads est buffer R (it-1), writes buffer W (it). No cross-block ordering needed.

__global__ __launch_bounds__(512) void k_iter(
    const u64* __restrict__ esR, const u64* __restrict__ ezR,
    u64* __restrict__ esW, u64* __restrict__ ezW,
    const u64* __restrict__ inb, const u64* __restrict__ cbbT,
    const unsigned char* __restrict__ cbFb,
    int* __restrict__ chg, int it)
{
  __shared__ u64 SL[16][128];
  __shared__ u64 NL[16][128];
  __shared__ int CL[16];
  __shared__ __align__(8) i8 A01[2 * 16 * 264];   // [p][b][m], row stride 264

  const int bid = blockIdx.x;
  const int f = bid & 3;
  const int dq = (bid >> 2) & 3;
  const int bg = bid >> 4;
  const int t = threadIdx.x;

  if (chg[it - 1] == 0) {
    // converged earlier: copy own slice forward so buffer parity stays valid
    const int b = bg * 16 + (t >> 5);
    const int w = dq * 32 + (t & 31);
    const size_t wi = ((size_t)(b * 4 + f)) * 128 + w;
    esW[wi] = esR[wi];
    ezW[wi] = ezR[wi];
    return;
  }

  int ffs[3];
  { int c = 0; for (int ff = 0; ff < 4; ++ff) if (ff != f) ffs[c++] = ff; }

  // ---- stage s = in ^ (xor of other-f est signs), nz = ~(or of other-f zero masks) ----
  #pragma unroll
  for (int k2 = 0; k2 < 4; ++k2) {
    const int pr = t + k2 * 512;          // 0..2047 = b(16) x w(128)
    const int b = pr >> 7, w = pr & 127;
    const int gbr = bg * 16 + b;
    const size_t base = (size_t)gbr * 512;
    u64 s = inb[(size_t)gbr * 128 + w]
      ^ esR[base + ffs[0] * 128 + w] ^ esR[base + ffs[1] * 128 + w] ^ esR[base + ffs[2] * 128 + w];
    u64 nz = ~(ezR[base + ffs[0] * 128 + w] | ezR[base + ffs[1] * 128 + w] | ezR[base + ffs[2] * 128 + w]);
    SL[b][w] = s;
    NL[b][w] = nz;
  }
  __syncthreads();

  if (t < 16) {
    int c = 0;
    for (int w = 0; w < 128; ++w) c += (int)__popcll(NL[t][w]);
    CL[t] = c;
  }

  // ---- sim via popcounts: thread = (m per-lane, 8 b wave-uniform) ----
  {
    const int m = t & 255;
    const int b8 = (t >> 8) * 8;
    int a[8];
    #pragma unroll
    for (int j = 0; j < 8; ++j) a[j] = 0;
    const u64* pc = cbbT + (size_t)f * 32768 + m;
    for (int w = 0; w < 128; ++w) {
      const u64 cbw = pc[w * 256];
      #pragma unroll
      for (int j = 0; j < 8; ++j)
        a[j] += (int)__popcll((SL[b8 + j][w] ^ cbw) & NL[b8 + j][w]);
    }
    __syncthreads();   // CL ready
    #pragma unroll
    for (int j = 0; j < 8; ++j) {
      const int sim = CL[b8 + j] - 2 * a[j];
      const int d1 = (sim + 128) >> 8;
      const int d0 = sim - (d1 << 8);
      A01[(0 * 16 + b8 + j) * 264 + m] = (i8)d0;
      A01[(1 * 16 + b8 + j) * 264 + m] = (i8)d1;
    }
  }
  __syncthreads();     // A01 ready

  // ---- GEMM: A[16 b][256 m] digits x B[256 m][2048 d] (packed bits, expanded in regs) ----
  const int lane = t & 63;
  const int wv = t >> 6;
  const int rsel = lane & 15;
  const int kq = lane >> 4;
  const int dbase = dq * 2048 + wv * 256;

  bool chl = false;

  #pragma unroll
  for (int c = 0; c < 4; ++c) {       // 4 chunks of 64 d per wave
    v4i acc[2][4];
    #pragma unroll
    for (int p = 0; p < 2; ++p)
      #pragma unroll
      for (int j = 0; j < 4; ++j) acc[p][j] = 0;

    #pragma unroll
    for (int ks = 0; ks < 8; ++ks) {
      const long af0 = *(const long*)&A01[(0 * 16 + rsel) * 264 + ks * 32 + kq * 8];
      const long af1 = *(const long*)&A01[(1 * 16 + rsel) * 264 + ks * 32 + kq * 8];
      #pragma unroll
      for (int j = 0; j < 4; ++j) {
        const int d0w = dbase + c * 64 + j * 16;
        const int dt = d0w >> 7;
        const int dsub = (d0w >> 4) & 7;
        const long bf = expand_pm1(
            cbFb[(size_t)(f * 64 + dt) * 4096 + (ks * 8 + dsub) * 64 + kq * 16 + rsel]);
        acc[0][j] = __builtin_amdgcn_mfma_i32_16x16x32_i8(af0, bf, acc[0][j], 0, 0, 0);
        acc[1][j] = __builtin_amdgcn_mfma_i32_16x16x32_i8(af1, bf, acc[1][j], 0, 0, 0);
      }
    }

    // epilogue: sign, ballot-pack 64 d bits per b, change-detect, store to W
    unsigned long long bs[4][4], bz[4][4];
    #pragma unroll
    for (int rr = 0; rr < 4; ++rr)
      #pragma unroll
      for (int j = 0; j < 4; ++j) {
        const int o = acc[0][j][rr] + acc[1][j][rr] * 256;
        bs[rr][j] = __ballot(o < 0);
        bz[rr][j] = __ballot(o == 0);
      }
    u64 ws = 0, wz = 0;
    #pragma unroll
    for (int rl = 0; rl < 16; ++rl) {
      const int g = rl >> 2, rr = rl & 3;
      u64 vs = 0, vz = 0;
      #pragma unroll
      for (int j = 0; j < 4; ++j) {
        vs |= ((bs[rr][j] >> (g * 16)) & 0xFFFFull) << (j * 16);
        vz |= ((bz[rr][j] >> (g * 16)) & 0xFFFFull) << (j * 16);
      }
      if (lane == rl) { ws = vs; wz = vz; }
    }
    if (lane < 16) {
      const int b = bg * 16 + lane;
      const int w = (dbase + c * 64) >> 6;
      const size_t wi = ((size_t)(b * 4 + f)) * 128 + w;
      chl |= (ws != esR[wi]) | (wz != ezR[wi]);
      esW[wi] = ws;
      ezW[wi] = wz;
    }
  }
  if (__any(chl)) { if (lane == 0) atomicOr(&chg[it], 1); }
}

// ---------------- final: sim + argmax + k (reads buffer 1) ----------------

__global__ __launch_bounds__(512) void k_final(
    const u64* __restrict__ esb, const u64* __restrict__ ezb,
    const u64* __restrict__ cbbT, const int* __restrict__ chg,
    int* __restrict__ out)
{
  __shared__ u64 AL[128][4];
  __shared__ long long red[2][256];

  const int bid = blockIdx.x;
  const int f = bid & 3;
  const int b0 = (bid >> 2) * 2;
  const int t = threadIdx.x;

  if (t < 256) {
    const int r = t >> 7, w = t & 127;
    const int b = b0 + r;
    const size_t a = ((size_t)b * 4 + f) * 128 + w;
    AL[w][r * 2] = esb[a];
    AL[w][r * 2 + 1] = ~ezb[a];
  }
  __syncthreads();

  const int r = t >> 8;
  const int m = t & 255;
  int a = 0, c = 0;
  const u64* pc = cbbT + (size_t)f * 32768 + m;
  #pragma unroll 8
  for (int w = 0; w < 128; ++w) {
    const u64 cbw = pc[w * 256];
    a += (int)__popcll((AL[w][r * 2] ^ cbw) & AL[w][r * 2 + 1]);
    c += (int)__popcll(AL[w][r * 2 + 1]);
  }
  const int sim = c - 2 * a;

  red[r][m] = ((long long)sim << 32) | (long long)(unsigned)(255 - m);
  __syncthreads();
  for (int s2 = 128; s2 > 0; s2 >>= 1) {
    if (m < s2) {
      if (red[r][m + s2] > red[r][m]) red[r][m] = red[r][m + s2];
    }
    __syncthreads();
  }
  if (m == 0) {
    out[(b0 + r) * 4 + f] = 255 - (int)(red[r][0] & 0xFFFF);
    if (t == 0 && bid == 0) {
      int k = NITER;
      for (int i = 1; i <= NITER; ++i) if (chg[i] == 0) { k = i; break; }
      out[B_SZ * F_SZ] = k;
    }
  }
}

// ---------------- host ----------------

extern "C" void kernel_launch(void* const* d_in, const int* in_sizes, int n_in,
                              void* d_out, int out_size, void* d_ws, size_t ws_size,
                              hipStream_t stream) {
  const float* f_in = (const float*)d_in[0];   // [B][D]
  const float* f_cb = (const float*)d_in[1];   // [F][M][D]
  int* out = (int*)d_out;
  char* ws = (char*)d_ws;

  i8*  cb8  = (i8*)(ws + OFF_CB);
  unsigned char* cbFb = (unsigned char*)(ws + OFF_CBFB);
  i8*  in8  = (i8*)(ws + OFF_IN8);
  u64* cbbT = (u64*)(ws + OFF_CBBT);
  u64* inb  = (u64*)(ws + OFF_INB);
  u64* esb0 = (u64*)(ws + OFF_ESB);
  u64* ezb0 = (u64*)(ws + OFF_EZB);
  u64* esb1 = (u64*)(ws + OFF_ESB1);
  u64* ezb1 = (u64*)(ws + OFF_EZB1);
  i8*  aF01 = (i8*)(ws + OFF_AF01);
  i8*  aF2  = (i8*)(ws + OFF_AF2);
  int* p1   = (int*)(ws + OFF_P1);
  int* S32  = (int*)(ws + OFF_S32);
  i8*  pdig = (i8*)(ws + OFF_PDIG);
  int* chg  = (int*)(ws + OFF_CHG);

  hipMemsetAsync(chg, 0, 64, stream);
  k_cvt_cb<<<dim3(8192), dim3(256), 0, stream>>>(f_cb, cb8, cbFb);
  k_cvt_in<<<dim3(2048), dim3(256), 0, stream>>>(f_in, in8);
  k_pack_cb<<<dim3(512), dim3(256), 0, stream>>>(cb8, cbbT);
  k_pack_in<<<dim3(128), dim3(256), 0, stream>>>(in8, inb);
  k_S<<<dim3(128), dim3(256), 0, stream>>>(cb8, S32);
  k_P<<<dim3(32), dim3(256), 0, stream>>>(S32, pdig);

  // iteration 1 (big-integer est0 via P/8 digit planes, MFMA) -> est buffer 0
  ga2_kernel<<<dim3(768), dim3(256), 0, stream>>>(in8, cb8, pdig, p1);
  k_digits1<<<dim3(1024), dim3(256), 0, stream>>>(p1, aF01, aF2);
  gb_first_k<<<dim3(1024), dim3(256), 0, stream>>>(aF01, aF2, cbFb, esb0, ezb0, S32, chg, 1);

  // iterations 2..10: merged sim+GEMM, ping-pong est buffers
  for (int it = 2; it <= NITER; ++it) {
    const u64 *eR, *zR;
    u64 *eW, *zW;
    if (it & 1) { eR = esb1; zR = ezb1; eW = esb0; zW = ezb0; }
    else        { eR = esb0; zR = ezb0; eW = esb1; zW = ezb1; }
    k_iter<<<dim3(256), dim3(512), 0, stream>>>(eR, zR, eW, zW, inb, cbbT, cbFb, chg, it);
  }

  // NITER=10 is even -> final state in buffer 1
  k_final<<<dim3(512), dim3(512), 0, stream>>>(esb1, ezb1, cbbT, chg, out);
}